// Round 5
// baseline (381.723 us; speedup 1.0000x reference)
//
#include <hip/hip_runtime.h>

// Problem constants (from reference):
//   B=8, S=4, L=512, H=768  -> hidden (8, 2048, 768) fp32 (50 MB)
//   N_SPANS=4096, T_MAX=16, N_PAIRS=16384
//   out[p] = [repr(pair_i[p]) | repr(pair_j[p])], repr = [first|mean|last] (9 KB)
//
// R5 structure: R3's fused scatter (best so far, ours ~175 us) + LOCALITY:
//   - spans are processed in (doc, tok0/128)-bucketed order,
//   - doc d is pinned to blocks with blockIdx % 8 == d (XCD round-robin),
//   so each XCD's 4 MB L2 sees one 6.3 MB doc walked in token order instead
//   of random rows from the whole 50 MB table. Gather -> L2 hits; kernel
//   falls toward the 302 MB write floor.
// Index machinery (4 tiny kernels, ~us): pair-use inverse map (span->targets)
// and the doc/token-bucket span ordering, built in the same passes.

#define SPAN_HF4  192          // H / 4 float4s
#define SPAN_TMAX 16
#define SPAN_SL   2048         // S * L
#define REPR_F4   576          // 3 * 192 float4 per span
#define OUT_F4    1152         // 2 * 576 float4 per pair
#define MAX_SPANS 4096         // scan kernel capacity (1024 thr x 4)
#define TOK_BUCKETS 16         // tok0 >> 7  (2048 / 16 = 128 tokens per bucket)
#define MAX_DOCS  16
#define BPD       576          // blocks per doc (avg 512 spans/doc + 3 sigma)

// Native clang vector: __builtin_nontemporal_store rejects HIP_vector_type.
typedef float f4nt __attribute__((ext_vector_type(4)));

__device__ __forceinline__ void nt_store_f4(const float4 v, float4* p) {
    f4nt t;
    t.x = v.x; t.y = v.y; t.z = v.z; t.w = v.w;
    __builtin_nontemporal_store(t, reinterpret_cast<f4nt*>(p));
}

// ---------------------------------------------------------------- index pass

__global__ void zero_kernel(int* __restrict__ pair_counts, int n_spans,
                            int* __restrict__ bucket_counts, int nbuckets) {
    const int i = blockIdx.x * blockDim.x + threadIdx.x;
    if (i < n_spans)  pair_counts[i] = 0;
    if (i < nbuckets) bucket_counts[i] = 0;
}

__global__ void count_kernel(const int* __restrict__ pair_i,
                             const int* __restrict__ pair_j, int n_pairs,
                             const int* __restrict__ span_doc,
                             const int* __restrict__ span_tok, int n_spans,
                             int* __restrict__ pair_counts,
                             int* __restrict__ bucket_counts) {
    const int i = blockIdx.x * blockDim.x + threadIdx.x;
    if (i < n_pairs) {
        atomicAdd(&pair_counts[pair_i[i]], 1);
        atomicAdd(&pair_counts[pair_j[i]], 1);
    }
    if (i < n_spans) {
        const int b = span_doc[i] * TOK_BUCKETS + (span_tok[i * SPAN_TMAX] >> 7);
        atomicAdd(&bucket_counts[b], 1);
    }
}

// Single block: exclusive scan of pair_counts (<=4096, 1024 thr x 4) and of
// bucket_counts (<=256, sequential on thread 0 -- trivial).
__global__ __launch_bounds__(1024)
void scan_kernel(const int* __restrict__ pair_counts,
                 int* __restrict__ offsets,        // n_spans+1
                 int* __restrict__ cursor,         // n_spans
                 int n_spans,
                 const int* __restrict__ bucket_counts,
                 int* __restrict__ bucket_offsets, // nbuckets+1
                 int* __restrict__ bucket_cursor,  // nbuckets
                 int nbuckets) {
    __shared__ int sums[1024];
    const int t = threadIdx.x;
    const int base = t * 4;
    int c0 = 0, c1 = 0, c2 = 0, c3 = 0;
    if (base     < n_spans) c0 = pair_counts[base];
    if (base + 1 < n_spans) c1 = pair_counts[base + 1];
    if (base + 2 < n_spans) c2 = pair_counts[base + 2];
    if (base + 3 < n_spans) c3 = pair_counts[base + 3];
    sums[t] = c0 + c1 + c2 + c3;
    __syncthreads();
    for (int off = 1; off < 1024; off <<= 1) {
        const int v = (t >= off) ? sums[t - off] : 0;
        __syncthreads();
        sums[t] += v;
        __syncthreads();
    }
    const int excl = (t == 0) ? 0 : sums[t - 1];
    const int o0 = excl, o1 = o0 + c0, o2 = o1 + c1, o3 = o2 + c2;
    if (base     < n_spans) { offsets[base]     = o0; cursor[base]     = o0; }
    if (base + 1 < n_spans) { offsets[base + 1] = o1; cursor[base + 1] = o1; }
    if (base + 2 < n_spans) { offsets[base + 2] = o2; cursor[base + 2] = o2; }
    if (base + 3 < n_spans) { offsets[base + 3] = o3; cursor[base + 3] = o3; }
    if (t == 1023) offsets[n_spans] = sums[1023];   // total = 2*n_pairs
    if (t == 0) {
        int acc = 0;
        for (int b = 0; b < nbuckets; ++b) {
            bucket_offsets[b] = acc;
            bucket_cursor[b]  = acc;
            acc += bucket_counts[b];
        }
        bucket_offsets[nbuckets] = acc;             // = n_spans
    }
}

__global__ void fill_kernel(const int* __restrict__ pair_i,
                            const int* __restrict__ pair_j, int n_pairs,
                            const int* __restrict__ span_doc,
                            const int* __restrict__ span_tok, int n_spans,
                            int* __restrict__ cursor,
                            int* __restrict__ targets,       // 2*n_pairs
                            int* __restrict__ bucket_cursor,
                            int* __restrict__ span_order) {  // n_spans
    const int i = blockIdx.x * blockDim.x + threadIdx.x;
    if (i < n_pairs) {
        const int a = atomicAdd(&cursor[pair_i[i]], 1);
        targets[a] = i * 2;          // side 0 (i-half)
        const int b = atomicAdd(&cursor[pair_j[i]], 1);
        targets[b] = i * 2 + 1;      // side 1 (j-half)
    }
    if (i < n_spans) {
        const int b = span_doc[i] * TOK_BUCKETS + (span_tok[i * SPAN_TMAX] >> 7);
        const int slot = atomicAdd(&bucket_cursor[b], 1);
        span_order[slot] = i;
    }
}

// ------------------------------------------------------------------ main pass

__global__ __launch_bounds__(192)
void span_scatter_kernel(
    const float4* __restrict__ hidden,    // (B, SL, HF4)
    const int*    __restrict__ span_doc,
    const int*    __restrict__ span_tok,  // (N_SPANS, TMAX)
    const int*    __restrict__ span_len,
    const int*    __restrict__ offsets,        // (n_spans+1)
    const int*    __restrict__ targets,        // (2*n_pairs): p*2+side
    const int*    __restrict__ bucket_offsets, // (ndocs*16+1)
    const int*    __restrict__ span_order,     // (n_spans), doc-major
    float4*       __restrict__ out,            // (N_PAIRS, 1152)
    int ndocs)
{
    const int c = threadIdx.x;                 // 0..191
    // Doc -> XCD affinity: blockIdx % ndocs (= %8) matches the round-robin
    // block->XCD dispatch, so each XCD's L2 walks ONE doc in token order.
    const int d      = blockIdx.x % ndocs;
    const int k0     = blockIdx.x / ndocs;
    const int stride = gridDim.x / ndocs;
    const int dbeg = bucket_offsets[d * TOK_BUCKETS];
    const int dend = bucket_offsets[(d + 1) * TOK_BUCKETS];

    __shared__ int tgt[192];

    for (int idx = dbeg + k0; idx < dend; idx += stride) {
        const int s = span_order[idx];

        const int len = span_len[s];           // block-uniform
        const int* toks = span_tok + s * SPAN_TMAX;
        const float4* base = hidden + (size_t)d * (SPAN_SL * SPAN_HF4);

        float4 first = make_float4(0.f, 0.f, 0.f, 0.f);
        float4 last  = make_float4(0.f, 0.f, 0.f, 0.f);
        float sx = 0.f, sy = 0.f, sz = 0.f, sw = 0.f;

        // Clamped unroll: 16 unconditional independent loads; `last` free.
        #pragma unroll
        for (int t = 0; t < SPAN_TMAX; ++t) {
            const int tc = (t < len) ? t : (len - 1);
            const float4 v = base[(size_t)toks[tc] * SPAN_HF4 + c];
            if (t == 0) first = v;
            last = v;
            const float m = (t < len) ? 1.f : 0.f;
            sx += v.x * m; sy += v.y * m; sz += v.z * m; sw += v.w * m;
        }

        const float inv = 1.0f / (float)len;
        const float4 a0 = first;
        const float4 a1 = make_float4(sx * inv, sy * inv, sz * inv, sw * inv);
        const float4 a2 = last;

        // Scatter to every (pair,side) slot referencing this span.
        const int start = offsets[s];
        const int end   = offsets[s + 1];
        for (int cb = start; cb < end; cb += 192) {
            const int n = min(192, end - cb);
            if (c < n) tgt[c] = targets[cb + c];
            __syncthreads();
            for (int k = 0; k < n; ++k) {
                const int tv = tgt[k];         // block-uniform
                float4* o = out + (size_t)(tv >> 1) * OUT_F4
                                + (size_t)(tv & 1) * REPR_F4;
                nt_store_f4(a0, &o[c]);
                nt_store_f4(a1, &o[SPAN_HF4 + c]);
                nt_store_f4(a2, &o[2 * SPAN_HF4 + c]);
            }
            __syncthreads();
        }
    }
}

// ------------------------------------------- fallback (no workspace needed)

__global__ __launch_bounds__(192)
void span_fused_kernel(
    const float4* __restrict__ hidden,
    const int*    __restrict__ span_doc,
    const int*    __restrict__ span_tok,
    const int*    __restrict__ span_len,
    const int*    __restrict__ pair_i,
    const int*    __restrict__ pair_j,
    float4*       __restrict__ out)
{
    const int p = blockIdx.x;
    const int c = threadIdx.x;
    const int si = pair_i[p];
    const int sj = pair_j[p];
    float4* orow = out + (size_t)p * OUT_F4;

    #pragma unroll
    for (int side = 0; side < 2; ++side) {
        const int s   = side ? sj : si;
        const int doc = span_doc[s];
        const int len = span_len[s];
        const int* toks = span_tok + s * SPAN_TMAX;
        const float4* base = hidden + (size_t)doc * (SPAN_SL * SPAN_HF4);

        float4 first = make_float4(0.f, 0.f, 0.f, 0.f);
        float4 last  = make_float4(0.f, 0.f, 0.f, 0.f);
        float sx = 0.f, sy = 0.f, sz = 0.f, sw = 0.f;
        #pragma unroll
        for (int t = 0; t < SPAN_TMAX; ++t) {
            const int tc = (t < len) ? t : (len - 1);
            const float4 v = base[(size_t)toks[tc] * SPAN_HF4 + c];
            if (t == 0) first = v;
            last = v;
            const float m = (t < len) ? 1.f : 0.f;
            sx += v.x * m; sy += v.y * m; sz += v.z * m; sw += v.w * m;
        }
        const float inv = 1.0f / (float)len;
        float4* o = orow + side * REPR_F4;
        nt_store_f4(first, &o[c]);
        nt_store_f4(make_float4(sx * inv, sy * inv, sz * inv, sw * inv),
                    &o[SPAN_HF4 + c]);
        nt_store_f4(last, &o[2 * SPAN_HF4 + c]);
    }
}

// ----------------------------------------------------------------- launcher

extern "C" void kernel_launch(void* const* d_in, const int* in_sizes, int n_in,
                              void* d_out, int out_size, void* d_ws, size_t ws_size,
                              hipStream_t stream) {
    const float4* hidden  = (const float4*)d_in[0];
    const int* span_doc   = (const int*)d_in[1];
    const int* span_tok   = (const int*)d_in[2];
    const int* span_len   = (const int*)d_in[3];
    const int* pair_i     = (const int*)d_in[4];
    const int* pair_j     = (const int*)d_in[5];
    float4* out           = (float4*)d_out;

    const int n_spans = in_sizes[1];                   // 4096 (elements)
    const int n_pairs = in_sizes[4];                   // 16384 (elements)
    const int ndocs   = in_sizes[0] / (SPAN_SL * 768); // 8

    // Workspace layout (16B-aligned sections, all int32):
    auto align16 = [](size_t x) { return (x + 15) & ~(size_t)15; };
    const int nbuckets = ndocs * TOK_BUCKETS;
    const size_t pc_b  = align16((size_t)n_spans * sizeof(int));        // pair_counts
    const size_t off_b = align16((size_t)(n_spans + 1) * sizeof(int));  // offsets
    const size_t cur_b = align16((size_t)n_spans * sizeof(int));        // cursor
    const size_t tgt_b = align16((size_t)2 * n_pairs * sizeof(int));    // targets
    const size_t bc_b  = align16((size_t)nbuckets * sizeof(int));       // bucket_counts
    const size_t bo_b  = align16((size_t)(nbuckets + 1) * sizeof(int)); // bucket_offsets
    const size_t bcu_b = align16((size_t)nbuckets * sizeof(int));       // bucket_cursor
    const size_t so_b  = align16((size_t)n_spans * sizeof(int));        // span_order
    const size_t need = pc_b + off_b + cur_b + tgt_b + bc_b + bo_b + bcu_b + so_b;

    if (n_spans <= MAX_SPANS && ndocs >= 1 && ndocs <= MAX_DOCS &&
        ws_size >= need) {
        char* ws = (char*)d_ws;
        int* pair_counts    = (int*)(ws);
        int* offsets        = (int*)(ws + pc_b);
        int* cursor         = (int*)(ws + pc_b + off_b);
        int* targets        = (int*)(ws + pc_b + off_b + cur_b);
        int* bucket_counts  = (int*)(ws + pc_b + off_b + cur_b + tgt_b);
        int* bucket_offsets = (int*)(ws + pc_b + off_b + cur_b + tgt_b + bc_b);
        int* bucket_cursor  = (int*)(ws + pc_b + off_b + cur_b + tgt_b + bc_b + bo_b);
        int* span_order     = (int*)(ws + pc_b + off_b + cur_b + tgt_b + bc_b + bo_b + bcu_b);

        const int zb = (max(n_spans, nbuckets) + 255) / 256;
        const int cb = (max(n_pairs, n_spans) + 255) / 256;
        zero_kernel<<<zb, 256, 0, stream>>>(pair_counts, n_spans,
                                            bucket_counts, nbuckets);
        count_kernel<<<cb, 256, 0, stream>>>(pair_i, pair_j, n_pairs,
                                             span_doc, span_tok, n_spans,
                                             pair_counts, bucket_counts);
        scan_kernel<<<1, 1024, 0, stream>>>(pair_counts, offsets, cursor, n_spans,
                                            bucket_counts, bucket_offsets,
                                            bucket_cursor, nbuckets);
        fill_kernel<<<cb, 256, 0, stream>>>(pair_i, pair_j, n_pairs,
                                            span_doc, span_tok, n_spans,
                                            cursor, targets,
                                            bucket_cursor, span_order);
        span_scatter_kernel<<<ndocs * BPD, 192, 0, stream>>>(
            hidden, span_doc, span_tok, span_len,
            offsets, targets, bucket_offsets, span_order, out, ndocs);
    } else {
        span_fused_kernel<<<n_pairs, 192, 0, stream>>>(
            hidden, span_doc, span_tok, span_len, pair_i, pair_j, out);
    }
}

// Round 6
// 363.905 us; speedup vs baseline: 1.0490x; 1.0490x over previous
//
#include <hip/hip_runtime.h>

// Problem constants (from reference):
//   B=8, S=4, L=512, H=768  -> hidden (8, 2048, 768) fp32 (50 MB)
//   N_SPANS=4096, T_MAX=16, N_PAIRS=16384
//   out[p] = [repr(pair_i[p]) | repr(pair_j[p])], repr = [first|mean|last] (9 KB)
//
// R6 structure: R3's fused scatter (best so far) made barrier-free + scalar.
//   - No LDS target staging: loop bounds forced to SGPR via readfirstlane,
//     so targets[k] is a uniform s_load; 4-way unroll keeps 4 in flight.
//     Removes 2 __syncthreads per span (each forced vmcnt(0) store drains
//     inside the block critical path).
//   - Block-uniform meta (doc/len/offsets) scalarized -> SALU address math,
//     toks via scalar path.
//   - nt stores for the 302 MB write stream (never re-read).
// Index machinery unchanged (zero/count/scan/fill -> span->targets map).

#define SPAN_HF4  192          // H / 4 float4s
#define SPAN_TMAX 16
#define SPAN_SL   2048         // S * L
#define REPR_F4   576          // 3 * 192 float4 per span
#define OUT_F4    1152         // 2 * 576 float4 per pair
#define MAX_SPANS 4096         // scan kernel capacity (1024 thr x 4)

// Native clang vector: __builtin_nontemporal_store rejects HIP_vector_type.
typedef float f4nt __attribute__((ext_vector_type(4)));

__device__ __forceinline__ void nt_store_f4(const float4 v, float4* p) {
    f4nt t;
    t.x = v.x; t.y = v.y; t.z = v.z; t.w = v.w;
    __builtin_nontemporal_store(t, reinterpret_cast<f4nt*>(p));
}

__device__ __forceinline__ void store_repr(float4* o, int c,
                                           const float4 a0, const float4 a1,
                                           const float4 a2) {
    nt_store_f4(a0, &o[c]);
    nt_store_f4(a1, &o[SPAN_HF4 + c]);
    nt_store_f4(a2, &o[2 * SPAN_HF4 + c]);
}

// ---------------------------------------------------------------- inverse map

__global__ void zero_counts_kernel(int* __restrict__ counts, int n) {
    const int i = blockIdx.x * blockDim.x + threadIdx.x;
    if (i < n) counts[i] = 0;
}

__global__ void count_uses_kernel(const int* __restrict__ pair_i,
                                  const int* __restrict__ pair_j,
                                  int* __restrict__ counts, int n_pairs) {
    const int p = blockIdx.x * blockDim.x + threadIdx.x;
    if (p < n_pairs) {
        atomicAdd(&counts[pair_i[p]], 1);
        atomicAdd(&counts[pair_j[p]], 1);
    }
}

// Single-block exclusive scan over <= 4096 counts (1024 threads x 4 elems).
__global__ __launch_bounds__(1024)
void scan_offsets_kernel(const int* __restrict__ counts,
                         int* __restrict__ offsets,   // n_spans+1 entries
                         int* __restrict__ cursor,    // n_spans entries
                         int n_spans) {
    __shared__ int sums[1024];
    const int t = threadIdx.x;
    const int base = t * 4;
    int c0 = 0, c1 = 0, c2 = 0, c3 = 0;
    if (base     < n_spans) c0 = counts[base];
    if (base + 1 < n_spans) c1 = counts[base + 1];
    if (base + 2 < n_spans) c2 = counts[base + 2];
    if (base + 3 < n_spans) c3 = counts[base + 3];
    sums[t] = c0 + c1 + c2 + c3;
    __syncthreads();
    // Hillis-Steele inclusive scan over the 1024 per-thread sums.
    for (int off = 1; off < 1024; off <<= 1) {
        const int v = (t >= off) ? sums[t - off] : 0;
        __syncthreads();
        sums[t] += v;
        __syncthreads();
    }
    const int excl = (t == 0) ? 0 : sums[t - 1];
    const int o0 = excl, o1 = o0 + c0, o2 = o1 + c1, o3 = o2 + c2;
    if (base     < n_spans) { offsets[base]     = o0; cursor[base]     = o0; }
    if (base + 1 < n_spans) { offsets[base + 1] = o1; cursor[base + 1] = o1; }
    if (base + 2 < n_spans) { offsets[base + 2] = o2; cursor[base + 2] = o2; }
    if (base + 3 < n_spans) { offsets[base + 3] = o3; cursor[base + 3] = o3; }
    if (t == 1023) offsets[n_spans] = sums[1023];   // total = 2*n_pairs
}

__global__ void fill_targets_kernel(const int* __restrict__ pair_i,
                                    const int* __restrict__ pair_j,
                                    int* __restrict__ cursor,
                                    int* __restrict__ targets,  // 2*n_pairs
                                    int n_pairs) {
    const int p = blockIdx.x * blockDim.x + threadIdx.x;
    if (p < n_pairs) {
        const int a = atomicAdd(&cursor[pair_i[p]], 1);
        targets[a] = p * 2;          // side 0 (i-half)
        const int b = atomicAdd(&cursor[pair_j[p]], 1);
        targets[b] = p * 2 + 1;      // side 1 (j-half)
    }
}

// ------------------------------------------------------------------ main pass

__global__ __launch_bounds__(192)
void span_scatter_kernel(
    const float4* __restrict__ hidden,    // (B, SL, HF4)
    const int*    __restrict__ span_doc,
    const int*    __restrict__ span_tok,  // (N_SPANS, TMAX)
    const int*    __restrict__ span_len,
    const int*    __restrict__ offsets,   // (n_spans+1)
    const int*    __restrict__ targets,   // (2*n_pairs): p*2+side
    float4*       __restrict__ out,       // (N_PAIRS, 1152)
    int n_spans)
{
    const int c = threadIdx.x;            // 0..191
    const int s = blockIdx.x;
    if (s >= n_spans) return;

    // Block-uniform metadata -> SGPRs (compiler can't prove uniformity).
    const int doc   = __builtin_amdgcn_readfirstlane(span_doc[s]);
    const int len   = __builtin_amdgcn_readfirstlane(span_len[s]);
    const int start = __builtin_amdgcn_readfirstlane(offsets[s]);
    const int end   = __builtin_amdgcn_readfirstlane(offsets[s + 1]);
    const int* toks = span_tok + s * SPAN_TMAX;
    const float4* base = hidden + (size_t)doc * (SPAN_SL * SPAN_HF4);

    // Gather: t = 0 peeled (len >= 1 always); remaining 15 loads clamped to
    // len-1 (valid addr, cache-hit) => 16 unconditional independent loads.
    float4 first, last;
    float sx, sy, sz, sw;
    {
        const float4 v = base[(size_t)toks[0] * SPAN_HF4 + c];
        first = v; last = v;
        sx = v.x; sy = v.y; sz = v.z; sw = v.w;
    }
    #pragma unroll
    for (int t = 1; t < SPAN_TMAX; ++t) {
        const int tc = (t < len) ? t : (len - 1);
        const float4 v = base[(size_t)toks[tc] * SPAN_HF4 + c];
        last = v;
        const float m = (t < len) ? 1.f : 0.f;
        sx += v.x * m; sy += v.y * m; sz += v.z * m; sw += v.w * m;
    }
    const float inv = 1.0f / (float)len;
    const float4 a1 = make_float4(sx * inv, sy * inv, sz * inv, sw * inv);

    // Scatter: uniform (SGPR) target indices, 4-way unrolled so 4 scalar
    // target loads are in flight; stores are fire-and-forget (no barriers,
    // drain only at kernel end).
    int k = start;
    for (; k + 4 <= end; k += 4) {
        const int t0 = __builtin_amdgcn_readfirstlane(targets[k]);
        const int t1 = __builtin_amdgcn_readfirstlane(targets[k + 1]);
        const int t2 = __builtin_amdgcn_readfirstlane(targets[k + 2]);
        const int t3 = __builtin_amdgcn_readfirstlane(targets[k + 3]);
        store_repr(out + (size_t)(t0 >> 1) * OUT_F4 + (size_t)(t0 & 1) * REPR_F4,
                   c, first, a1, last);
        store_repr(out + (size_t)(t1 >> 1) * OUT_F4 + (size_t)(t1 & 1) * REPR_F4,
                   c, first, a1, last);
        store_repr(out + (size_t)(t2 >> 1) * OUT_F4 + (size_t)(t2 & 1) * REPR_F4,
                   c, first, a1, last);
        store_repr(out + (size_t)(t3 >> 1) * OUT_F4 + (size_t)(t3 & 1) * REPR_F4,
                   c, first, a1, last);
    }
    for (; k < end; ++k) {
        const int tv = __builtin_amdgcn_readfirstlane(targets[k]);
        store_repr(out + (size_t)(tv >> 1) * OUT_F4 + (size_t)(tv & 1) * REPR_F4,
                   c, first, a1, last);
    }
}

// ------------------------------------------- fallback (no workspace needed)

__global__ __launch_bounds__(192)
void span_fused_kernel(
    const float4* __restrict__ hidden,
    const int*    __restrict__ span_doc,
    const int*    __restrict__ span_tok,
    const int*    __restrict__ span_len,
    const int*    __restrict__ pair_i,
    const int*    __restrict__ pair_j,
    float4*       __restrict__ out)
{
    const int p = blockIdx.x;
    const int c = threadIdx.x;
    const int si = pair_i[p];
    const int sj = pair_j[p];
    float4* orow = out + (size_t)p * OUT_F4;

    #pragma unroll
    for (int side = 0; side < 2; ++side) {
        const int s   = side ? sj : si;
        const int doc = span_doc[s];
        const int len = span_len[s];
        const int* toks = span_tok + s * SPAN_TMAX;
        const float4* base = hidden + (size_t)doc * (SPAN_SL * SPAN_HF4);

        float4 first = make_float4(0.f, 0.f, 0.f, 0.f);
        float4 last  = make_float4(0.f, 0.f, 0.f, 0.f);
        float sx = 0.f, sy = 0.f, sz = 0.f, sw = 0.f;
        #pragma unroll
        for (int t = 0; t < SPAN_TMAX; ++t) {
            const int tc = (t < len) ? t : (len - 1);
            const float4 v = base[(size_t)toks[tc] * SPAN_HF4 + c];
            if (t == 0) first = v;
            last = v;
            const float m = (t < len) ? 1.f : 0.f;
            sx += v.x * m; sy += v.y * m; sz += v.z * m; sw += v.w * m;
        }
        const float inv = 1.0f / (float)len;
        float4* o = orow + side * REPR_F4;
        nt_store_f4(first, &o[c]);
        nt_store_f4(make_float4(sx * inv, sy * inv, sz * inv, sw * inv),
                    &o[SPAN_HF4 + c]);
        nt_store_f4(last, &o[2 * SPAN_HF4 + c]);
    }
}

// ----------------------------------------------------------------- launcher

extern "C" void kernel_launch(void* const* d_in, const int* in_sizes, int n_in,
                              void* d_out, int out_size, void* d_ws, size_t ws_size,
                              hipStream_t stream) {
    const float4* hidden  = (const float4*)d_in[0];
    const int* span_doc   = (const int*)d_in[1];
    const int* span_tok   = (const int*)d_in[2];
    const int* span_len   = (const int*)d_in[3];
    const int* pair_i     = (const int*)d_in[4];
    const int* pair_j     = (const int*)d_in[5];
    float4* out           = (float4*)d_out;

    const int n_spans = in_sizes[1];      // 4096
    const int n_pairs = in_sizes[4];      // 16384

    // Workspace layout (16B-aligned sections):
    //   counts  : n_spans ints
    //   offsets : n_spans+1 ints
    //   cursor  : n_spans ints
    //   targets : 2*n_pairs ints
    auto align16 = [](size_t x) { return (x + 15) & ~(size_t)15; };
    const size_t counts_b  = align16((size_t)n_spans * sizeof(int));
    const size_t offsets_b = align16((size_t)(n_spans + 1) * sizeof(int));
    const size_t cursor_b  = align16((size_t)n_spans * sizeof(int));
    const size_t targets_b = align16((size_t)2 * n_pairs * sizeof(int));
    const size_t need = counts_b + offsets_b + cursor_b + targets_b;

    if (n_spans <= MAX_SPANS && ws_size >= need) {
        char* ws = (char*)d_ws;
        int* counts  = (int*)(ws);
        int* offsets = (int*)(ws + counts_b);
        int* cursor  = (int*)(ws + counts_b + offsets_b);
        int* targets = (int*)(ws + counts_b + offsets_b + cursor_b);

        const int zb = (n_spans + 255) / 256;
        const int pb = (n_pairs + 255) / 256;
        zero_counts_kernel<<<zb, 256, 0, stream>>>(counts, n_spans);
        count_uses_kernel<<<pb, 256, 0, stream>>>(pair_i, pair_j, counts, n_pairs);
        scan_offsets_kernel<<<1, 1024, 0, stream>>>(counts, offsets, cursor, n_spans);
        fill_targets_kernel<<<pb, 256, 0, stream>>>(pair_i, pair_j, cursor, targets, n_pairs);
        span_scatter_kernel<<<n_spans, 192, 0, stream>>>(
            hidden, span_doc, span_tok, span_len, offsets, targets, out, n_spans);
    } else {
        span_fused_kernel<<<n_pairs, 192, 0, stream>>>(
            hidden, span_doc, span_tok, span_len, pair_i, pair_j, out);
    }
}